// Round 21
// baseline (411.590 us; speedup 1.0000x reference)
//
#include <hip/hip_runtime.h>
#include <math.h>

#define D 128
#define NT 32    // nodes per block (transform)
#define AGT 16   // nodes per block (aggate)
#define LP 132   // padded f32 LDS row
#define CSB 256  // CSR pipeline blocks (first CSB blocks of the grid; co-resident)

__device__ __forceinline__ float wave_allsum(float v) {
    #pragma unroll
    for (int off = 32; off; off >>= 1) v += __shfl_xor(v, off);
    return v;
}

// ======================= launch 1: CSR pipeline (blocks 0..CSB-1) + transform =======
__global__ void __launch_bounds__(256) fused_csr_transform(
    const int* __restrict__ ei, int* __restrict__ deg, int* __restrict__ ctr,
    int* __restrict__ bsum, int* __restrict__ off, int* __restrict__ cursor,
    int* __restrict__ ssrc, int E,
    const float* __restrict__ x, const float* __restrict__ W1, const float* __restrict__ b1,
    const float* __restrict__ g1, const float* __restrict__ bt1,
    const float* __restrict__ We1, const float* __restrict__ be1,
    float* __restrict__ AH, float* __restrict__ B, int N)
{
    if (blockIdx.x < CSB) {
        __shared__ int red[256];
        __shared__ int bofs;
        const int b = blockIdx.x, t = threadIdx.x;

        // phase H: histogram
        for (int e = b * 256 + t; e < E; e += CSB * 256)
            atomicAdd(&deg[ei[E + e]], 1);
        __threadfence();
        __syncthreads();
        if (t == 0) {
            atomicAdd(&ctr[0], 1);
            while (atomicAdd(&ctr[0], 0) < CSB) __builtin_amdgcn_s_sleep(2);
        }
        __syncthreads();

        // phase A: per-thread chunk sums + block sum -> bsum[b]
        const int C = (N + CSB - 1) / CSB;
        const int W = (C + 255) / 256;
        int s0 = b * C + t * W;
        int s1 = min(s0 + W, min((b + 1) * C, N));
        int s = 0;
        for (int i = s0; i < s1; ++i) s += atomicAdd(&deg[i], 0);
        red[t] = s;
        __syncthreads();
        #pragma unroll
        for (int d = 128; d; d >>= 1) {
            if (t < d) red[t] += red[t + d];
            __syncthreads();
        }
        if (t == 0) atomicExch(&bsum[b], red[0]);
        __threadfence();
        __syncthreads();
        if (t == 0) {
            atomicAdd(&ctr[1], 1);
            while (atomicAdd(&ctr[1], 0) < CSB) __builtin_amdgcn_s_sleep(2);
        }
        __syncthreads();

        // phase C: block base + thread prefix -> off/cursor
        if (t == 0) {
            int r = 0;
            for (int i = 0; i < b; ++i) r += atomicAdd(&bsum[i], 0);
            bofs = r;
            if (b == CSB - 1) atomicExch(&off[N], r + atomicAdd(&bsum[b], 0));
        }
        red[t] = s;
        __syncthreads();
        for (int d = 1; d < 256; d <<= 1) {
            int vv = (t >= d) ? red[t - d] : 0;
            __syncthreads();
            if (t >= d) red[t] += vv;
            __syncthreads();
        }
        int run = bofs + ((t == 0) ? 0 : red[t - 1]);
        for (int i = s0; i < s1; ++i) {
            int dv = atomicAdd(&deg[i], 0);
            atomicExch(&off[i], run);
            atomicExch(&cursor[i], run);
            run += dv;
        }
        __threadfence();
        __syncthreads();
        if (t == 0) {
            atomicAdd(&ctr[2], 1);
            while (atomicAdd(&ctr[2], 0) < CSB) __builtin_amdgcn_s_sleep(2);
        }
        __syncthreads();

        // phase S: scatter (ssrc consumed by the NEXT kernel -> plain stores OK)
        for (int e = b * 256 + t; e < E; e += CSB * 256) {
            int pos = atomicAdd(&cursor[ei[E + e]], 1);
            ssrc[pos] = ei[e];
        }
        return;
    }

    // ---------------- transform ----------------
    __shared__ float xs[NT][LP];   // x, then h in place (wave-local)
    const int t = threadIdx.x;
    const int q = t >> 6, lane = t & 63;
    const int cg = (lane & 31) * 4;
    const int kh = (lane >> 5) * 64;
    const int khi = lane >> 5;
    const int base = (blockIdx.x - CSB) * NT;

    {
        int node = t >> 3, c0 = (t & 7) * 16;
        int gn = min(base + node, N - 1);
        const float4* src = (const float4*)(x + (size_t)gn * D + c0);
        float4* dst = (float4*)&xs[node][c0];
        dst[0] = src[0]; dst[1] = src[1]; dst[2] = src[2]; dst[3] = src[3];
    }

    float4 acc[8];
    #pragma unroll
    for (int n = 0; n < 8; ++n) acc[n] = make_float4(0.f,0.f,0.f,0.f);
    for (int k4 = 0; k4 < 16; ++k4) {
        int k = kh + k4 * 4;
        float4 w0 = *(const float4*)&W1[(k+0) * 128 + cg];
        float4 w1 = *(const float4*)&W1[(k+1) * 128 + cg];
        float4 w2 = *(const float4*)&W1[(k+2) * 128 + cg];
        float4 w3 = *(const float4*)&W1[(k+3) * 128 + cg];
        #pragma unroll
        for (int n = 0; n < 8; ++n) {
            float4 xv = *(const float4*)&xs[q*8+n][k];
            acc[n].x += xv.x*w0.x + xv.y*w1.x + xv.z*w2.x + xv.w*w3.x;
            acc[n].y += xv.x*w0.y + xv.y*w1.y + xv.z*w2.y + xv.w*w3.y;
            acc[n].z += xv.x*w0.z + xv.y*w1.z + xv.z*w2.z + xv.w*w3.z;
            acc[n].w += xv.x*w0.w + xv.y*w1.w + xv.z*w2.w + xv.w*w3.w;
        }
    }
    #pragma unroll
    for (int n = 0; n < 8; ++n) {
        acc[n].x += __shfl_xor(acc[n].x, 32);
        acc[n].y += __shfl_xor(acc[n].y, 32);
        acc[n].z += __shfl_xor(acc[n].z, 32);
        acc[n].w += __shfl_xor(acc[n].w, 32);
    }

    {
        float4 b4 = *(const float4*)&b1[cg];
        float4 g4 = *(const float4*)&g1[cg];
        float4 t4 = *(const float4*)&bt1[cg];
        #pragma unroll
        for (int n = 0; n < 8; ++n) {
            int node = q * 8 + n;
            float v0 = acc[n].x + b4.x, v1 = acc[n].y + b4.y;
            float v2 = acc[n].z + b4.z, v3 = acc[n].w + b4.w;
            float s  = wave_allsum(v0 + v1 + v2 + v3) * 0.5f;
            float qq = wave_allsum(v0*v0 + v1*v1 + v2*v2 + v3*v3) * 0.5f;
            float m = s * (1.f/128.f);
            float var = qq * (1.f/128.f) - m*m;
            float rs = rsqrtf(var + 1e-5f);
            float4 h4;
            h4.x = fmaxf((v0 - m)*rs*g4.x + t4.x, 0.f);
            h4.y = fmaxf((v1 - m)*rs*g4.y + t4.y, 0.f);
            h4.z = fmaxf((v2 - m)*rs*g4.z + t4.z, 0.f);
            h4.w = fmaxf((v3 - m)*rs*g4.w + t4.w, 0.f);
            if (khi == 0) {
                *(float4*)&xs[node][cg] = h4;
                int gn = base + node;
                if (gn < N) *(float4*)&AH[(size_t)gn * 256 + 128 + cg] = h4;
            }
        }
    }

    float4 aA[8], aB[8];
    #pragma unroll
    for (int n = 0; n < 8; ++n) { aA[n] = make_float4(0.f,0.f,0.f,0.f); aB[n] = make_float4(0.f,0.f,0.f,0.f); }
    for (int k4 = 0; k4 < 16; ++k4) {
        int k = kh + k4 * 4;
        float4 t0 = *(const float4*)&We1[(k+0) * 128 + cg];
        float4 t1 = *(const float4*)&We1[(k+1) * 128 + cg];
        float4 t2 = *(const float4*)&We1[(k+2) * 128 + cg];
        float4 t3 = *(const float4*)&We1[(k+3) * 128 + cg];
        float4 u0 = *(const float4*)&We1[(k+128) * 128 + cg];
        float4 u1 = *(const float4*)&We1[(k+129) * 128 + cg];
        float4 u2 = *(const float4*)&We1[(k+130) * 128 + cg];
        float4 u3 = *(const float4*)&We1[(k+131) * 128 + cg];
        #pragma unroll
        for (int n = 0; n < 8; ++n) {
            float4 hv = *(const float4*)&xs[q*8+n][k];
            aA[n].x += hv.x*t0.x + hv.y*t1.x + hv.z*t2.x + hv.w*t3.x;
            aA[n].y += hv.x*t0.y + hv.y*t1.y + hv.z*t2.y + hv.w*t3.y;
            aA[n].z += hv.x*t0.z + hv.y*t1.z + hv.z*t2.z + hv.w*t3.z;
            aA[n].w += hv.x*t0.w + hv.y*t1.w + hv.z*t2.w + hv.w*t3.w;
            aB[n].x += hv.x*u0.x + hv.y*u1.x + hv.z*u2.x + hv.w*u3.x;
            aB[n].y += hv.x*u0.y + hv.y*u1.y + hv.z*u2.y + hv.w*u3.y;
            aB[n].z += hv.x*u0.z + hv.y*u1.z + hv.z*u2.z + hv.w*u3.z;
            aB[n].w += hv.x*u0.w + hv.y*u1.w + hv.z*u2.w + hv.w*u3.w;
        }
    }
    {
        float4 be4 = *(const float4*)&be1[cg];
        #pragma unroll
        for (int n = 0; n < 8; ++n) {
            aA[n].x += __shfl_xor(aA[n].x, 32);
            aA[n].y += __shfl_xor(aA[n].y, 32);
            aA[n].z += __shfl_xor(aA[n].z, 32);
            aA[n].w += __shfl_xor(aA[n].w, 32);
            aB[n].x += __shfl_xor(aB[n].x, 32);
            aB[n].y += __shfl_xor(aB[n].y, 32);
            aB[n].z += __shfl_xor(aB[n].z, 32);
            aB[n].w += __shfl_xor(aB[n].w, 32);
            int gn = base + q*8 + n;
            if (khi == 0 && gn < N) {
                float4 a4 = make_float4(aA[n].x + be4.x, aA[n].y + be4.y,
                                        aA[n].z + be4.z, aA[n].w + be4.w);
                *(float4*)&AH[(size_t)gn * 256 + cg] = a4;
                *(float4*)&B[(size_t)gn * D + cg]    = aB[n];
            }
        }
    }
}

// ======================= launch 2: fused pull-aggregation + gate + final LN =======
__global__ void __launch_bounds__(256) aggate(
    const int* __restrict__ off, const int* __restrict__ ssrc,
    const float* __restrict__ AH, const float* __restrict__ B,
    const float* __restrict__ We2, const float* __restrict__ be2,
    const float* __restrict__ Wg, const float* __restrict__ bg,
    const float* __restrict__ g2, const float* __restrict__ bt2,
    float* __restrict__ out, int N)
{
    __shared__ float hs[AGT][LP];
    __shared__ float ag[AGT][LP];
    const int t = threadIdx.x;
    const int q = t >> 6, lane = t & 63;
    const int g = lane >> 4;
    const int c8 = (lane & 15) * 8;
    const int base = blockIdx.x * AGT;

    {
        int node = t >> 4, c0 = (t & 15) * 8;
        size_t gofs = (size_t)min(base + node, N - 1) * 256 + 128 + c0;
        const float4* src = (const float4*)(AH + gofs);
        float4* dst = (float4*)&hs[node][c0];
        dst[0] = src[0]; dst[1] = src[1];
    }

    {
        const float4* Wp = (const float4*)(We2 + c8);
        float4 w0 = Wp[0], w1 = Wp[1];
        const float be = be2[0];

        for (int n = 0; n < 4; ++n) {
            int node = base + q * 4 + n;
            float4 acc0 = make_float4(0.f,0.f,0.f,0.f);
            float4 acc1 = make_float4(0.f,0.f,0.f,0.f);
            if (node < N) {
                const int s = off[node], e = off[node + 1];
                const int deg = e - s;
                if (deg > 0) {
                    const float4* Bp = (const float4*)(B + (size_t)node * D + c8);
                    float4 b0 = Bp[0], b1 = Bp[1];
                    if (deg <= 64) {
                        int myidx = ssrc[min(s + lane, e - 1)];
                        const int nit = (deg + 7) >> 3;
                        for (int it = 0; it < nit; ++it) {
                            int ja = it * 8 + g * 2;
                            int jb = ja + 1;
                            int sa = __shfl(myidx, min(ja, deg - 1));
                            int sb = __shfl(myidx, min(jb, deg - 1));
                            const float4* Ra = (const float4*)(AH + (size_t)sa * 256 + c8);
                            const float4* Rb = (const float4*)(AH + (size_t)sb * 256 + c8);
                            float4 aa0 = Ra[0], aa1 = Ra[1];
                            float4 ha0 = Ra[32], ha1 = Ra[33];
                            float4 ab0 = Rb[0], ab1 = Rb[1];
                            float4 hb0 = Rb[32], hb1 = Rb[33];
                            float da = fmaxf(aa0.x + b0.x, 0.f) * w0.x + fmaxf(aa0.y + b0.y, 0.f) * w0.y
                                     + fmaxf(aa0.z + b0.z, 0.f) * w0.z + fmaxf(aa0.w + b0.w, 0.f) * w0.w
                                     + fmaxf(aa1.x + b1.x, 0.f) * w1.x + fmaxf(aa1.y + b1.y, 0.f) * w1.y
                                     + fmaxf(aa1.z + b1.z, 0.f) * w1.z + fmaxf(aa1.w + b1.w, 0.f) * w1.w;
                            float db = fmaxf(ab0.x + b0.x, 0.f) * w0.x + fmaxf(ab0.y + b0.y, 0.f) * w0.y
                                     + fmaxf(ab0.z + b0.z, 0.f) * w0.z + fmaxf(ab0.w + b0.w, 0.f) * w0.w
                                     + fmaxf(ab1.x + b1.x, 0.f) * w1.x + fmaxf(ab1.y + b1.y, 0.f) * w1.y
                                     + fmaxf(ab1.z + b1.z, 0.f) * w1.z + fmaxf(ab1.w + b1.w, 0.f) * w1.w;
                            da += __shfl_xor(da, 1);  db += __shfl_xor(db, 1);
                            da += __shfl_xor(da, 2);  db += __shfl_xor(db, 2);
                            da += __shfl_xor(da, 4);  db += __shfl_xor(db, 4);
                            da += __shfl_xor(da, 8);  db += __shfl_xor(db, 8);
                            float wa = (ja < deg) ? 1.f / (1.f + expf(-(da + be))) : 0.f;
                            float wb = (jb < deg) ? 1.f / (1.f + expf(-(db + be))) : 0.f;
                            acc0.x += wa * ha0.x + wb * hb0.x; acc0.y += wa * ha0.y + wb * hb0.y;
                            acc0.z += wa * ha0.z + wb * hb0.z; acc0.w += wa * ha0.w + wb * hb0.w;
                            acc1.x += wa * ha1.x + wb * hb1.x; acc1.y += wa * ha1.y + wb * hb1.y;
                            acc1.z += wa * ha1.z + wb * hb1.z; acc1.w += wa * ha1.w + wb * hb1.w;
                        }
                    } else {
                        const int nit = (deg + 7) >> 3;
                        for (int it = 0; it < nit; ++it) {
                            int ja = s + it * 8 + g * 2;
                            int jb = ja + 1;
                            int sa = ssrc[min(ja, e - 1)];
                            int sb = ssrc[min(jb, e - 1)];
                            const float4* Ra = (const float4*)(AH + (size_t)sa * 256 + c8);
                            const float4* Rb = (const float4*)(AH + (size_t)sb * 256 + c8);
                            float4 aa0 = Ra[0], aa1 = Ra[1];
                            float4 ha0 = Ra[32], ha1 = Ra[33];
                            float4 ab0 = Rb[0], ab1 = Rb[1];
                            float4 hb0 = Rb[32], hb1 = Rb[33];
                            float da = fmaxf(aa0.x + b0.x, 0.f) * w0.x + fmaxf(aa0.y + b0.y, 0.f) * w0.y
                                     + fmaxf(aa0.z + b0.z, 0.f) * w0.z + fmaxf(aa0.w + b0.w, 0.f) * w0.w
                                     + fmaxf(aa1.x + b1.x, 0.f) * w1.x + fmaxf(aa1.y + b1.y, 0.f) * w1.y
                                     + fmaxf(aa1.z + b1.z, 0.f) * w1.z + fmaxf(aa1.w + b1.w, 0.f) * w1.w;
                            float db = fmaxf(ab0.x + b0.x, 0.f) * w0.x + fmaxf(ab0.y + b0.y, 0.f) * w0.y
                                     + fmaxf(ab0.z + b0.z, 0.f) * w0.z + fmaxf(ab0.w + b0.w, 0.f) * w0.w
                                     + fmaxf(ab1.x + b1.x, 0.f) * w1.x + fmaxf(ab1.y + b1.y, 0.f) * w1.y
                                     + fmaxf(ab1.z + b1.z, 0.f) * w1.z + fmaxf(ab1.w + b1.w, 0.f) * w1.w;
                            da += __shfl_xor(da, 1);  db += __shfl_xor(db, 1);
                            da += __shfl_xor(da, 2);  db += __shfl_xor(db, 2);
                            da += __shfl_xor(da, 4);  db += __shfl_xor(db, 4);
                            da += __shfl_xor(da, 8);  db += __shfl_xor(db, 8);
                            float wa = (ja < e) ? 1.f / (1.f + expf(-(da + be))) : 0.f;
                            float wb = (jb < e) ? 1.f / (1.f + expf(-(db + be))) : 0.f;
                            acc0.x += wa * ha0.x + wb * hb0.x; acc0.y += wa * ha0.y + wb * hb0.y;
                            acc0.z += wa * ha0.z + wb * hb0.z; acc0.w += wa * ha0.w + wb * hb0.w;
                            acc1.x += wa * ha1.x + wb * hb1.x; acc1.y += wa * ha1.y + wb * hb1.y;
                            acc1.z += wa * ha1.z + wb * hb1.z; acc1.w += wa * ha1.w + wb * hb1.w;
                        }
                    }
                    #pragma unroll
                    for (int o = 16; o <= 32; o <<= 1) {
                        acc0.x += __shfl_xor(acc0.x, o); acc0.y += __shfl_xor(acc0.y, o);
                        acc0.z += __shfl_xor(acc0.z, o); acc0.w += __shfl_xor(acc0.w, o);
                        acc1.x += __shfl_xor(acc1.x, o); acc1.y += __shfl_xor(acc1.y, o);
                        acc1.z += __shfl_xor(acc1.z, o); acc1.w += __shfl_xor(acc1.w, o);
                    }
                }
            }
            if (g == 0) {
                *(float4*)&ag[q*4+n][c8]     = acc0;
                *(float4*)&ag[q*4+n][c8 + 4] = acc1;
            }
        }
    }

    {
        const int cg = (lane & 31) * 4;
        const int kh = (lane >> 5) * 64;
        const int khi = lane >> 5;

        float4 acc[4];
        #pragma unroll
        for (int n = 0; n < 4; ++n) acc[n] = make_float4(0.f,0.f,0.f,0.f);
        for (int k4 = 0; k4 < 16; ++k4) {
            int k = kh + k4 * 4;
            float4 w0 = *(const float4*)&Wg[(k+0) * 128 + cg];
            float4 w1 = *(const float4*)&Wg[(k+1) * 128 + cg];
            float4 w2 = *(const float4*)&Wg[(k+2) * 128 + cg];
            float4 w3 = *(const float4*)&Wg[(k+3) * 128 + cg];
            float4 u0 = *(const float4*)&Wg[(k+128) * 128 + cg];
            float4 u1 = *(const float4*)&Wg[(k+129) * 128 + cg];
            float4 u2 = *(const float4*)&Wg[(k+130) * 128 + cg];
            float4 u3 = *(const float4*)&Wg[(k+131) * 128 + cg];
            #pragma unroll
            for (int n = 0; n < 4; ++n) {
                float4 v = *(const float4*)&hs[q*4+n][k];
                float4 a = *(const float4*)&ag[q*4+n][k];
                acc[n].x += v.x*w0.x + v.y*w1.x + v.z*w2.x + v.w*w3.x
                          + a.x*u0.x + a.y*u1.x + a.z*u2.x + a.w*u3.x;
                acc[n].y += v.x*w0.y + v.y*w1.y + v.z*w2.y + v.w*w3.y
                          + a.x*u0.y + a.y*u1.y + a.z*u2.y + a.w*u3.y;
                acc[n].z += v.x*w0.z + v.y*w1.z + v.z*w2.z + v.w*w3.z
                          + a.x*u0.z + a.y*u1.z + a.z*u2.z + a.w*u3.z;
                acc[n].w += v.x*w0.w + v.y*w1.w + v.z*w2.w + v.w*w3.w
                          + a.x*u0.w + a.y*u1.w + a.z*u2.w + a.w*u3.w;
            }
        }
        #pragma unroll
        for (int n = 0; n < 4; ++n) {
            acc[n].x += __shfl_xor(acc[n].x, 32);
            acc[n].y += __shfl_xor(acc[n].y, 32);
            acc[n].z += __shfl_xor(acc[n].z, 32);
            acc[n].w += __shfl_xor(acc[n].w, 32);
        }

        float4 bg4 = *(const float4*)&bg[cg];
        float4 gg4 = *(const float4*)&g2[cg];
        float4 bb4 = *(const float4*)&bt2[cg];
        #pragma unroll
        for (int n = 0; n < 4; ++n) {
            int node = q*4 + n;
            float4 av = *(const float4*)&ag[node][cg];
            float4 hv = *(const float4*)&hs[node][cg];
            float g0 = 1.f / (1.f + expf(-(acc[n].x + bg4.x)));
            float g1v = 1.f / (1.f + expf(-(acc[n].y + bg4.y)));
            float g2v = 1.f / (1.f + expf(-(acc[n].z + bg4.z)));
            float g3 = 1.f / (1.f + expf(-(acc[n].w + bg4.w)));
            float y0 = g0 * av.x + (1.f - g0) * hv.x;
            float y1 = g1v * av.y + (1.f - g1v) * hv.y;
            float y2 = g2v * av.z + (1.f - g2v) * hv.z;
            float y3 = g3 * av.w + (1.f - g3) * hv.w;
            float s  = wave_allsum(y0 + y1 + y2 + y3) * 0.5f;
            float qq = wave_allsum(y0*y0 + y1*y1 + y2*y2 + y3*y3) * 0.5f;
            float m = s * (1.f/128.f);
            float var = qq * (1.f/128.f) - m*m;
            float rs = rsqrtf(var + 1e-5f);
            int gn = base + node;
            if (khi == 0 && gn < N) {
                float4 o4;
                o4.x = (y0 - m)*rs*gg4.x + bb4.x;
                o4.y = (y1 - m)*rs*gg4.y + bb4.y;
                o4.z = (y2 - m)*rs*gg4.z + bb4.z;
                o4.w = (y3 - m)*rs*gg4.w + bb4.w;
                *(float4*)&out[(size_t)gn * D + cg] = o4;
            }
        }
    }
}

extern "C" void kernel_launch(void* const* d_in, const int* in_sizes, int n_in,
                              void* d_out, int out_size, void* d_ws, size_t ws_size,
                              hipStream_t stream) {
    const float* x   = (const float*)d_in[0];
    const int*   ei  = (const int*)d_in[1];
    const float* W1  = (const float*)d_in[2];
    const float* b1  = (const float*)d_in[3];
    const float* g1  = (const float*)d_in[4];
    const float* bt1 = (const float*)d_in[5];
    const float* We1 = (const float*)d_in[6];
    const float* be1 = (const float*)d_in[7];
    const float* We2 = (const float*)d_in[8];
    const float* be2 = (const float*)d_in[9];
    const float* Wg  = (const float*)d_in[14];
    const float* bg  = (const float*)d_in[15];
    const float* g2  = (const float*)d_in[16];
    const float* bt2 = (const float*)d_in[17];

    const int N = in_sizes[0] / D;
    const int E = in_sizes[1] / 2;
    const size_t ND = (size_t)N * D;

    float* AH   = (float*)d_ws;          // N x 256 (A | h)
    float* B    = AH + 2 * ND;
    int* deg    = (int*)(B + ND);        // N+1
    int* ctr    = deg + (N + 1);         // 8 barrier counters
    int* off    = ctr + 8;               // N+1
    int* cursor = off + (N + 1);         // N+1
    int* ssrc   = cursor + (N + 1);      // E
    int* bsum   = ssrc + E;              // CSB

    (void)hipMemsetAsync(deg, 0, (size_t)(N + 1 + 8) * sizeof(int), stream);

    const int nblkT = (N + NT - 1) / NT;
    fused_csr_transform<<<CSB + nblkT, 256, 0, stream>>>(
        ei, deg, ctr, bsum, off, cursor, ssrc, E,
        x, W1, b1, g1, bt1, We1, be1, AH, B, N);
    aggate<<<(N + AGT - 1) / AGT, 256, 0, stream>>>(off, ssrc, AH, B, We2, be2,
                                                    Wg, bg, g2, bt2, (float*)d_out, N);
}

// Round 22
// 308.035 us; speedup vs baseline: 1.3362x; 1.3362x over previous
//
#include <hip/hip_runtime.h>
#include <math.h>

#define D 128
#define NT 32    // nodes per block (transform)
#define AGT 16   // nodes per block (aggate)
#define LP 132   // padded f32 LDS row
#define CSB 64   // CSR pipeline blocks (co-resident; 64 proved the sweet spot)

__device__ __forceinline__ float wave_allsum(float v) {
    #pragma unroll
    for (int off = 32; off; off >>= 1) v += __shfl_xor(v, off);
    return v;
}

// ======================= launch 1: CSR pipeline (blocks 0..CSB-1) + transform =======
__global__ void __launch_bounds__(256) fused_csr_transform(
    const int* __restrict__ ei, int* __restrict__ deg, int* __restrict__ ctr,
    int* __restrict__ bsum, int* __restrict__ off, int* __restrict__ cursor,
    int* __restrict__ ssrc, int E,
    const float* __restrict__ x, const float* __restrict__ W1, const float* __restrict__ b1,
    const float* __restrict__ g1, const float* __restrict__ bt1,
    const float* __restrict__ We1, const float* __restrict__ be1,
    float* __restrict__ AH, float* __restrict__ B, int N)
{
    if (blockIdx.x < CSB) {
        __builtin_amdgcn_s_setprio(1);   // CSR blocks get issue preference (T5)
        __shared__ int red[256];
        __shared__ int bofs;
        const int b = blockIdx.x, t = threadIdx.x;

        // phase H: histogram
        for (int e = b * 256 + t; e < E; e += CSB * 256)
            atomicAdd(&deg[ei[E + e]], 1);
        __threadfence();
        __syncthreads();
        if (t == 0) {
            atomicAdd(&ctr[0], 1);
            while (atomicAdd(&ctr[0], 0) < CSB) __builtin_amdgcn_s_sleep(32);
        }
        __syncthreads();

        // phase A: per-thread chunk sums + block sum -> bsum[b]
        const int C = (N + CSB - 1) / CSB;
        const int W = (C + 255) / 256;
        int s0 = b * C + t * W;
        int s1 = min(s0 + W, min((b + 1) * C, N));
        int s = 0;
        for (int i = s0; i < s1; ++i) s += atomicAdd(&deg[i], 0);
        red[t] = s;
        __syncthreads();
        #pragma unroll
        for (int d = 128; d; d >>= 1) {
            if (t < d) red[t] += red[t + d];
            __syncthreads();
        }
        if (t == 0) atomicExch(&bsum[b], red[0]);
        __threadfence();
        __syncthreads();
        if (t == 0) {
            atomicAdd(&ctr[1], 1);
            while (atomicAdd(&ctr[1], 0) < CSB) __builtin_amdgcn_s_sleep(32);
        }
        __syncthreads();

        // phase C: block base + thread prefix -> off/cursor
        if (t == 0) {
            int r = 0;
            for (int i = 0; i < b; ++i) r += atomicAdd(&bsum[i], 0);
            bofs = r;
            if (b == CSB - 1) atomicExch(&off[N], r + atomicAdd(&bsum[b], 0));
        }
        red[t] = s;
        __syncthreads();
        for (int d = 1; d < 256; d <<= 1) {
            int vv = (t >= d) ? red[t - d] : 0;
            __syncthreads();
            if (t >= d) red[t] += vv;
            __syncthreads();
        }
        int run = bofs + ((t == 0) ? 0 : red[t - 1]);
        for (int i = s0; i < s1; ++i) {
            int dv = atomicAdd(&deg[i], 0);
            atomicExch(&off[i], run);
            atomicExch(&cursor[i], run);
            run += dv;
        }
        __threadfence();
        __syncthreads();
        if (t == 0) {
            atomicAdd(&ctr[2], 1);
            while (atomicAdd(&ctr[2], 0) < CSB) __builtin_amdgcn_s_sleep(32);
        }
        __syncthreads();

        // phase S: scatter (ssrc consumed by the NEXT kernel -> plain stores OK)
        for (int e = b * 256 + t; e < E; e += CSB * 256) {
            int pos = atomicAdd(&cursor[ei[E + e]], 1);
            ssrc[pos] = ei[e];
        }
        __builtin_amdgcn_s_setprio(0);
        return;
    }

    // ---------------- transform ----------------
    __shared__ float xs[NT][LP];   // x, then h in place (wave-local)
    const int t = threadIdx.x;
    const int q = t >> 6, lane = t & 63;
    const int cg = (lane & 31) * 4;
    const int kh = (lane >> 5) * 64;
    const int khi = lane >> 5;
    const int base = (blockIdx.x - CSB) * NT;

    {
        int node = t >> 3, c0 = (t & 7) * 16;
        int gn = min(base + node, N - 1);
        const float4* src = (const float4*)(x + (size_t)gn * D + c0);
        float4* dst = (float4*)&xs[node][c0];
        dst[0] = src[0]; dst[1] = src[1]; dst[2] = src[2]; dst[3] = src[3];
    }

    float4 acc[8];
    #pragma unroll
    for (int n = 0; n < 8; ++n) acc[n] = make_float4(0.f,0.f,0.f,0.f);
    for (int k4 = 0; k4 < 16; ++k4) {
        int k = kh + k4 * 4;
        float4 w0 = *(const float4*)&W1[(k+0) * 128 + cg];
        float4 w1 = *(const float4*)&W1[(k+1) * 128 + cg];
        float4 w2 = *(const float4*)&W1[(k+2) * 128 + cg];
        float4 w3 = *(const float4*)&W1[(k+3) * 128 + cg];
        #pragma unroll
        for (int n = 0; n < 8; ++n) {
            float4 xv = *(const float4*)&xs[q*8+n][k];
            acc[n].x += xv.x*w0.x + xv.y*w1.x + xv.z*w2.x + xv.w*w3.x;
            acc[n].y += xv.x*w0.y + xv.y*w1.y + xv.z*w2.y + xv.w*w3.y;
            acc[n].z += xv.x*w0.z + xv.y*w1.z + xv.z*w2.z + xv.w*w3.z;
            acc[n].w += xv.x*w0.w + xv.y*w1.w + xv.z*w2.w + xv.w*w3.w;
        }
    }
    #pragma unroll
    for (int n = 0; n < 8; ++n) {
        acc[n].x += __shfl_xor(acc[n].x, 32);
        acc[n].y += __shfl_xor(acc[n].y, 32);
        acc[n].z += __shfl_xor(acc[n].z, 32);
        acc[n].w += __shfl_xor(acc[n].w, 32);
    }

    {
        float4 b4 = *(const float4*)&b1[cg];
        float4 g4 = *(const float4*)&g1[cg];
        float4 t4 = *(const float4*)&bt1[cg];
        #pragma unroll
        for (int n = 0; n < 8; ++n) {
            int node = q * 8 + n;
            float v0 = acc[n].x + b4.x, v1 = acc[n].y + b4.y;
            float v2 = acc[n].z + b4.z, v3 = acc[n].w + b4.w;
            float s  = wave_allsum(v0 + v1 + v2 + v3) * 0.5f;
            float qq = wave_allsum(v0*v0 + v1*v1 + v2*v2 + v3*v3) * 0.5f;
            float m = s * (1.f/128.f);
            float var = qq * (1.f/128.f) - m*m;
            float rs = rsqrtf(var + 1e-5f);
            float4 h4;
            h4.x = fmaxf((v0 - m)*rs*g4.x + t4.x, 0.f);
            h4.y = fmaxf((v1 - m)*rs*g4.y + t4.y, 0.f);
            h4.z = fmaxf((v2 - m)*rs*g4.z + t4.z, 0.f);
            h4.w = fmaxf((v3 - m)*rs*g4.w + t4.w, 0.f);
            if (khi == 0) {
                *(float4*)&xs[node][cg] = h4;
                int gn = base + node;
                if (gn < N) *(float4*)&AH[(size_t)gn * 256 + 128 + cg] = h4;
            }
        }
    }

    float4 aA[8], aB[8];
    #pragma unroll
    for (int n = 0; n < 8; ++n) { aA[n] = make_float4(0.f,0.f,0.f,0.f); aB[n] = make_float4(0.f,0.f,0.f,0.f); }
    for (int k4 = 0; k4 < 16; ++k4) {
        int k = kh + k4 * 4;
        float4 t0 = *(const float4*)&We1[(k+0) * 128 + cg];
        float4 t1 = *(const float4*)&We1[(k+1) * 128 + cg];
        float4 t2 = *(const float4*)&We1[(k+2) * 128 + cg];
        float4 t3 = *(const float4*)&We1[(k+3) * 128 + cg];
        float4 u0 = *(const float4*)&We1[(k+128) * 128 + cg];
        float4 u1 = *(const float4*)&We1[(k+129) * 128 + cg];
        float4 u2 = *(const float4*)&We1[(k+130) * 128 + cg];
        float4 u3 = *(const float4*)&We1[(k+131) * 128 + cg];
        #pragma unroll
        for (int n = 0; n < 8; ++n) {
            float4 hv = *(const float4*)&xs[q*8+n][k];
            aA[n].x += hv.x*t0.x + hv.y*t1.x + hv.z*t2.x + hv.w*t3.x;
            aA[n].y += hv.x*t0.y + hv.y*t1.y + hv.z*t2.y + hv.w*t3.y;
            aA[n].z += hv.x*t0.z + hv.y*t1.z + hv.z*t2.z + hv.w*t3.z;
            aA[n].w += hv.x*t0.w + hv.y*t1.w + hv.z*t2.w + hv.w*t3.w;
            aB[n].x += hv.x*u0.x + hv.y*u1.x + hv.z*u2.x + hv.w*u3.x;
            aB[n].y += hv.x*u0.y + hv.y*u1.y + hv.z*u2.y + hv.w*u3.y;
            aB[n].z += hv.x*u0.z + hv.y*u1.z + hv.z*u2.z + hv.w*u3.z;
            aB[n].w += hv.x*u0.w + hv.y*u1.w + hv.z*u2.w + hv.w*u3.w;
        }
    }
    {
        float4 be4 = *(const float4*)&be1[cg];
        #pragma unroll
        for (int n = 0; n < 8; ++n) {
            aA[n].x += __shfl_xor(aA[n].x, 32);
            aA[n].y += __shfl_xor(aA[n].y, 32);
            aA[n].z += __shfl_xor(aA[n].z, 32);
            aA[n].w += __shfl_xor(aA[n].w, 32);
            aB[n].x += __shfl_xor(aB[n].x, 32);
            aB[n].y += __shfl_xor(aB[n].y, 32);
            aB[n].z += __shfl_xor(aB[n].z, 32);
            aB[n].w += __shfl_xor(aB[n].w, 32);
            int gn = base + q*8 + n;
            if (khi == 0 && gn < N) {
                float4 a4 = make_float4(aA[n].x + be4.x, aA[n].y + be4.y,
                                        aA[n].z + be4.z, aA[n].w + be4.w);
                *(float4*)&AH[(size_t)gn * 256 + cg] = a4;
                *(float4*)&B[(size_t)gn * D + cg]    = aB[n];
            }
        }
    }
}

// ======================= launch 2: fused pull-aggregation + gate + final LN =======
__global__ void __launch_bounds__(256) aggate(
    const int* __restrict__ off, const int* __restrict__ ssrc,
    const float* __restrict__ AH, const float* __restrict__ B,
    const float* __restrict__ We2, const float* __restrict__ be2,
    const float* __restrict__ Wg, const float* __restrict__ bg,
    const float* __restrict__ g2, const float* __restrict__ bt2,
    float* __restrict__ out, int N)
{
    __shared__ float hs[AGT][LP];
    __shared__ float ag[AGT][LP];
    const int t = threadIdx.x;
    const int q = t >> 6, lane = t & 63;
    const int g = lane >> 4;
    const int c8 = (lane & 15) * 8;
    const int base = blockIdx.x * AGT;

    {
        int node = t >> 4, c0 = (t & 15) * 8;
        size_t gofs = (size_t)min(base + node, N - 1) * 256 + 128 + c0;
        const float4* src = (const float4*)(AH + gofs);
        float4* dst = (float4*)&hs[node][c0];
        dst[0] = src[0]; dst[1] = src[1];
    }

    {
        const float4* Wp = (const float4*)(We2 + c8);
        float4 w0 = Wp[0], w1 = Wp[1];
        const float be = be2[0];

        for (int n = 0; n < 4; ++n) {
            int node = base + q * 4 + n;
            float4 acc0 = make_float4(0.f,0.f,0.f,0.f);
            float4 acc1 = make_float4(0.f,0.f,0.f,0.f);
            if (node < N) {
                const int s = off[node], e = off[node + 1];
                const int deg = e - s;
                if (deg > 0) {
                    const float4* Bp = (const float4*)(B + (size_t)node * D + c8);
                    float4 b0 = Bp[0], b1 = Bp[1];
                    if (deg <= 64) {
                        int myidx = ssrc[min(s + lane, e - 1)];
                        const int nit = (deg + 7) >> 3;
                        for (int it = 0; it < nit; ++it) {
                            int ja = it * 8 + g * 2;
                            int jb = ja + 1;
                            int sa = __shfl(myidx, min(ja, deg - 1));
                            int sb = __shfl(myidx, min(jb, deg - 1));
                            const float4* Ra = (const float4*)(AH + (size_t)sa * 256 + c8);
                            const float4* Rb = (const float4*)(AH + (size_t)sb * 256 + c8);
                            float4 aa0 = Ra[0], aa1 = Ra[1];
                            float4 ha0 = Ra[32], ha1 = Ra[33];
                            float4 ab0 = Rb[0], ab1 = Rb[1];
                            float4 hb0 = Rb[32], hb1 = Rb[33];
                            float da = fmaxf(aa0.x + b0.x, 0.f) * w0.x + fmaxf(aa0.y + b0.y, 0.f) * w0.y
                                     + fmaxf(aa0.z + b0.z, 0.f) * w0.z + fmaxf(aa0.w + b0.w, 0.f) * w0.w
                                     + fmaxf(aa1.x + b1.x, 0.f) * w1.x + fmaxf(aa1.y + b1.y, 0.f) * w1.y
                                     + fmaxf(aa1.z + b1.z, 0.f) * w1.z + fmaxf(aa1.w + b1.w, 0.f) * w1.w;
                            float db = fmaxf(ab0.x + b0.x, 0.f) * w0.x + fmaxf(ab0.y + b0.y, 0.f) * w0.y
                                     + fmaxf(ab0.z + b0.z, 0.f) * w0.z + fmaxf(ab0.w + b0.w, 0.f) * w0.w
                                     + fmaxf(ab1.x + b1.x, 0.f) * w1.x + fmaxf(ab1.y + b1.y, 0.f) * w1.y
                                     + fmaxf(ab1.z + b1.z, 0.f) * w1.z + fmaxf(ab1.w + b1.w, 0.f) * w1.w;
                            da += __shfl_xor(da, 1);  db += __shfl_xor(db, 1);
                            da += __shfl_xor(da, 2);  db += __shfl_xor(db, 2);
                            da += __shfl_xor(da, 4);  db += __shfl_xor(db, 4);
                            da += __shfl_xor(da, 8);  db += __shfl_xor(db, 8);
                            float wa = (ja < deg) ? 1.f / (1.f + expf(-(da + be))) : 0.f;
                            float wb = (jb < deg) ? 1.f / (1.f + expf(-(db + be))) : 0.f;
                            acc0.x += wa * ha0.x + wb * hb0.x; acc0.y += wa * ha0.y + wb * hb0.y;
                            acc0.z += wa * ha0.z + wb * hb0.z; acc0.w += wa * ha0.w + wb * hb0.w;
                            acc1.x += wa * ha1.x + wb * hb1.x; acc1.y += wa * ha1.y + wb * hb1.y;
                            acc1.z += wa * ha1.z + wb * hb1.z; acc1.w += wa * ha1.w + wb * hb1.w;
                        }
                    } else {
                        const int nit = (deg + 7) >> 3;
                        for (int it = 0; it < nit; ++it) {
                            int ja = s + it * 8 + g * 2;
                            int jb = ja + 1;
                            int sa = ssrc[min(ja, e - 1)];
                            int sb = ssrc[min(jb, e - 1)];
                            const float4* Ra = (const float4*)(AH + (size_t)sa * 256 + c8);
                            const float4* Rb = (const float4*)(AH + (size_t)sb * 256 + c8);
                            float4 aa0 = Ra[0], aa1 = Ra[1];
                            float4 ha0 = Ra[32], ha1 = Ra[33];
                            float4 ab0 = Rb[0], ab1 = Rb[1];
                            float4 hb0 = Rb[32], hb1 = Rb[33];
                            float da = fmaxf(aa0.x + b0.x, 0.f) * w0.x + fmaxf(aa0.y + b0.y, 0.f) * w0.y
                                     + fmaxf(aa0.z + b0.z, 0.f) * w0.z + fmaxf(aa0.w + b0.w, 0.f) * w0.w
                                     + fmaxf(aa1.x + b1.x, 0.f) * w1.x + fmaxf(aa1.y + b1.y, 0.f) * w1.y
                                     + fmaxf(aa1.z + b1.z, 0.f) * w1.z + fmaxf(aa1.w + b1.w, 0.f) * w1.w;
                            float db = fmaxf(ab0.x + b0.x, 0.f) * w0.x + fmaxf(ab0.y + b0.y, 0.f) * w0.y
                                     + fmaxf(ab0.z + b0.z, 0.f) * w0.z + fmaxf(ab0.w + b0.w, 0.f) * w0.w
                                     + fmaxf(ab1.x + b1.x, 0.f) * w1.x + fmaxf(ab1.y + b1.y, 0.f) * w1.y
                                     + fmaxf(ab1.z + b1.z, 0.f) * w1.z + fmaxf(ab1.w + b1.w, 0.f) * w1.w;
                            da += __shfl_xor(da, 1);  db += __shfl_xor(db, 1);
                            da += __shfl_xor(da, 2);  db += __shfl_xor(db, 2);
                            da += __shfl_xor(da, 4);  db += __shfl_xor(db, 4);
                            da += __shfl_xor(da, 8);  db += __shfl_xor(db, 8);
                            float wa = (ja < e) ? 1.f / (1.f + expf(-(da + be))) : 0.f;
                            float wb = (jb < e) ? 1.f / (1.f + expf(-(db + be))) : 0.f;
                            acc0.x += wa * ha0.x + wb * hb0.x; acc0.y += wa * ha0.y + wb * hb0.y;
                            acc0.z += wa * ha0.z + wb * hb0.z; acc0.w += wa * ha0.w + wb * hb0.w;
                            acc1.x += wa * ha1.x + wb * hb1.x; acc1.y += wa * ha1.y + wb * hb1.y;
                            acc1.z += wa * ha1.z + wb * hb1.z; acc1.w += wa * ha1.w + wb * hb1.w;
                        }
                    }
                    #pragma unroll
                    for (int o = 16; o <= 32; o <<= 1) {
                        acc0.x += __shfl_xor(acc0.x, o); acc0.y += __shfl_xor(acc0.y, o);
                        acc0.z += __shfl_xor(acc0.z, o); acc0.w += __shfl_xor(acc0.w, o);
                        acc1.x += __shfl_xor(acc1.x, o); acc1.y += __shfl_xor(acc1.y, o);
                        acc1.z += __shfl_xor(acc1.z, o); acc1.w += __shfl_xor(acc1.w, o);
                    }
                }
            }
            if (g == 0) {
                *(float4*)&ag[q*4+n][c8]     = acc0;
                *(float4*)&ag[q*4+n][c8 + 4] = acc1;
            }
        }
    }

    {
        const int cg = (lane & 31) * 4;
        const int kh = (lane >> 5) * 64;
        const int khi = lane >> 5;

        float4 acc[4];
        #pragma unroll
        for (int n = 0; n < 4; ++n) acc[n] = make_float4(0.f,0.f,0.f,0.f);
        for (int k4 = 0; k4 < 16; ++k4) {
            int k = kh + k4 * 4;
            float4 w0 = *(const float4*)&Wg[(k+0) * 128 + cg];
            float4 w1 = *(const float4*)&Wg[(k+1) * 128 + cg];
            float4 w2 = *(const float4*)&Wg[(k+2) * 128 + cg];
            float4 w3 = *(const float4*)&Wg[(k+3) * 128 + cg];
            float4 u0 = *(const float4*)&Wg[(k+128) * 128 + cg];
            float4 u1 = *(const float4*)&Wg[(k+129) * 128 + cg];
            float4 u2 = *(const float4*)&Wg[(k+130) * 128 + cg];
            float4 u3 = *(const float4*)&Wg[(k+131) * 128 + cg];
            #pragma unroll
            for (int n = 0; n < 4; ++n) {
                float4 v = *(const float4*)&hs[q*4+n][k];
                float4 a = *(const float4*)&ag[q*4+n][k];
                acc[n].x += v.x*w0.x + v.y*w1.x + v.z*w2.x + v.w*w3.x
                          + a.x*u0.x + a.y*u1.x + a.z*u2.x + a.w*u3.x;
                acc[n].y += v.x*w0.y + v.y*w1.y + v.z*w2.y + v.w*w3.y
                          + a.x*u0.y + a.y*u1.y + a.z*u2.y + a.w*u3.y;
                acc[n].z += v.x*w0.z + v.y*w1.z + v.z*w2.z + v.w*w3.z
                          + a.x*u0.z + a.y*u1.z + a.z*u2.z + a.w*u3.z;
                acc[n].w += v.x*w0.w + v.y*w1.w + v.z*w2.w + v.w*w3.w
                          + a.x*u0.w + a.y*u1.w + a.z*u2.w + a.w*u3.w;
            }
        }
        #pragma unroll
        for (int n = 0; n < 4; ++n) {
            acc[n].x += __shfl_xor(acc[n].x, 32);
            acc[n].y += __shfl_xor(acc[n].y, 32);
            acc[n].z += __shfl_xor(acc[n].z, 32);
            acc[n].w += __shfl_xor(acc[n].w, 32);
        }

        float4 bg4 = *(const float4*)&bg[cg];
        float4 gg4 = *(const float4*)&g2[cg];
        float4 bb4 = *(const float4*)&bt2[cg];
        #pragma unroll
        for (int n = 0; n < 4; ++n) {
            int node = q*4 + n;
            float4 av = *(const float4*)&ag[node][cg];
            float4 hv = *(const float4*)&hs[node][cg];
            float g0 = 1.f / (1.f + expf(-(acc[n].x + bg4.x)));
            float g1v = 1.f / (1.f + expf(-(acc[n].y + bg4.y)));
            float g2v = 1.f / (1.f + expf(-(acc[n].z + bg4.z)));
            float g3 = 1.f / (1.f + expf(-(acc[n].w + bg4.w)));
            float y0 = g0 * av.x + (1.f - g0) * hv.x;
            float y1 = g1v * av.y + (1.f - g1v) * hv.y;
            float y2 = g2v * av.z + (1.f - g2v) * hv.z;
            float y3 = g3 * av.w + (1.f - g3) * hv.w;
            float s  = wave_allsum(y0 + y1 + y2 + y3) * 0.5f;
            float qq = wave_allsum(y0*y0 + y1*y1 + y2*y2 + y3*y3) * 0.5f;
            float m = s * (1.f/128.f);
            float var = qq * (1.f/128.f) - m*m;
            float rs = rsqrtf(var + 1e-5f);
            int gn = base + node;
            if (khi == 0 && gn < N) {
                float4 o4;
                o4.x = (y0 - m)*rs*gg4.x + bb4.x;
                o4.y = (y1 - m)*rs*gg4.y + bb4.y;
                o4.z = (y2 - m)*rs*gg4.z + bb4.z;
                o4.w = (y3 - m)*rs*gg4.w + bb4.w;
                *(float4*)&out[(size_t)gn * D + cg] = o4;
            }
        }
    }
}

extern "C" void kernel_launch(void* const* d_in, const int* in_sizes, int n_in,
                              void* d_out, int out_size, void* d_ws, size_t ws_size,
                              hipStream_t stream) {
    const float* x   = (const float*)d_in[0];
    const int*   ei  = (const int*)d_in[1];
    const float* W1  = (const float*)d_in[2];
    const float* b1  = (const float*)d_in[3];
    const float* g1  = (const float*)d_in[4];
    const float* bt1 = (const float*)d_in[5];
    const float* We1 = (const float*)d_in[6];
    const float* be1 = (const float*)d_in[7];
    const float* We2 = (const float*)d_in[8];
    const float* be2 = (const float*)d_in[9];
    const float* Wg  = (const float*)d_in[14];
    const float* bg  = (const float*)d_in[15];
    const float* g2  = (const float*)d_in[16];
    const float* bt2 = (const float*)d_in[17];

    const int N = in_sizes[0] / D;
    const int E = in_sizes[1] / 2;
    const size_t ND = (size_t)N * D;

    float* AH   = (float*)d_ws;          // N x 256 (A | h)
    float* B    = AH + 2 * ND;
    int* deg    = (int*)(B + ND);        // N+1
    int* ctr    = deg + (N + 1);         // 8 barrier counters
    int* off    = ctr + 8;               // N+1
    int* cursor = off + (N + 1);         // N+1
    int* ssrc   = cursor + (N + 1);      // E
    int* bsum   = ssrc + E;              // CSB

    (void)hipMemsetAsync(deg, 0, (size_t)(N + 1 + 8) * sizeof(int), stream);

    const int nblkT = (N + NT - 1) / NT;
    fused_csr_transform<<<CSB + nblkT, 256, 0, stream>>>(
        ei, deg, ctr, bsum, off, cursor, ssrc, E,
        x, W1, b1, g1, bt1, We1, be1, AH, B, N);
    aggate<<<(N + AGT - 1) / AGT, 256, 0, stream>>>(off, ssrc, AH, B, We2, be2,
                                                    Wg, bg, g2, bt2, (float*)d_out, N);
}